// Round 16
// baseline (221.646 us; speedup 1.0000x reference)
//
#include <hip/hip_runtime.h>

#define N_NODES 40000
#define N_EDGES 640000
#define HD 128
#define N_REL2 474
#define BN_EPS 1e-5f

typedef _Float16 half8 __attribute__((ext_vector_type(8)));
typedef float f32x4 __attribute__((ext_vector_type(4)));

// K1: transposed nibble counts: word = [(node>>5)*480 + rel]*4 + ((node&31)>>3)
__global__ __launch_bounds__(256) void k_cnt(
        const int* __restrict__ dst, const int* __restrict__ rel_id,
        unsigned* __restrict__ cntT) {
    int e = blockIdx.x * 256 + threadIdx.x;
    if (e < N_EDGES) {
        int d = dst[e], r = rel_id[e];
        int nb = d >> 5, lrow = d & 31;
        atomicAdd(&cntT[(size_t)(nb * 480 + r) * 4 + (lrow >> 3)], 1u << ((lrow & 7) * 4));
    }
}

// K2: R_hl = fp16 hi|lo of rel_emb ([480][256], pad rows zero);
//     RWT = (rel_emb @ neigh_w)^T fp16 hi|lo ([128][960]: hi 480 | lo 480)
__global__ __launch_bounds__(128) void k_rw(
        const float* __restrict__ R, const float* __restrict__ W,
        _Float16* __restrict__ R_hl, _Float16* __restrict__ RWT) {
    __shared__ float row[HD];
    int r = blockIdx.x, c = threadIdx.x;
    float rv = (r < N_REL2) ? R[(size_t)r * HD + c] : 0.f;
    row[c] = rv;
    _Float16 hh = (_Float16)rv;
    R_hl[r * 256 + c] = hh;
    R_hl[r * 256 + 128 + c] = (_Float16)(rv - (float)hh);
    __syncthreads();
    float acc = 0.f;
    #pragma unroll 8
    for (int k = 0; k < HD; ++k) acc += row[k] * W[(size_t)k * HD + c];
    _Float16 ah = (_Float16)acc;
    RWT[c * 960 + r] = ah;
    RWT[c * 960 + 480 + r] = (_Float16)(acc - (float)ah);
}

// K3 (fat v4): 32 nodes/block, 4 waves; wave owns 16 full rows x 240-col half.
// B operands DIRECT FROM GLOBAL (L2-resident R_hl/RWT; R13-proven addressing).
// Only 3 barriers in the whole kernel. LDS 41 KB -> 3 blocks/CU.
__global__ __launch_bounds__(256, 3) void k_fat(
        const float* __restrict__ ent, const _Float16* __restrict__ R_hl,
        const _Float16* __restrict__ RWT, const unsigned* __restrict__ cntT,
        float* __restrict__ h) {
    __shared__ __align__(16) unsigned char lds[41344];
    _Float16* As  = (_Float16*)lds;               // [32][488] halfs (31232 B)
    unsigned* cl  = (unsigned*)(lds + 31232);     // [480][5] u32 (9600 B)
    float*    mh  = (float*)(lds + 40832);        // [2][32]
    float*    lsu = (float*)(lds + 41088);        // [2][32]

    int t = threadIdx.x, w = t >> 6, l = t & 63, lr = l & 15, lk = l >> 4;
    int nb = blockIdx.x;
    int rh = w & 1, ch = w >> 1;
    int node = nb * 32 + rh * 16 + lr;

    // stage transposed cnt words (consumed after barrier 1)
    const unsigned* cg = cntT + (size_t)nb * 1920;
    for (int i = t; i < 1920; i += 256)
        cl[(i >> 2) * 5 + (i & 3)] = cg[i];

    f32x4 acc[15];
    #pragma unroll
    for (int i = 0; i < 15; ++i) acc[i] = (f32x4){0.f, 0.f, 0.f, 0.f};

    // ---- GEMM1: G(16 rows x 240 cols per wave), B direct from L2, no barriers ----
    for (int kf = 0; kf < 4; ++kf) {
        const float* ep = ent + (size_t)node * HD + kf * 32 + lk * 8;
        float4 v0 = *(const float4*)ep;
        float4 v1 = *(const float4*)(ep + 4);
        float vv[8] = {v0.x, v0.y, v0.z, v0.w, v1.x, v1.y, v1.z, v1.w};
        half8 ah, al;
        #pragma unroll
        for (int j = 0; j < 8; ++j) {
            _Float16 hh = (_Float16)vv[j];
            ah[j] = hh;
            al[j] = (_Float16)(vv[j] - (float)hh);
        }
        #pragma unroll
        for (int tl = 0; tl < 15; ++tl) {
            const _Float16* bp = R_hl + (size_t)(ch * 240 + tl * 16 + lr) * 256 + kf * 32 + lk * 8;
            half8 bh = *(const half8*)bp;
            half8 bl = *(const half8*)(bp + 128);
            acc[tl] = __builtin_amdgcn_mfma_f32_16x16x32_f16(ah, bh, acc[tl], 0, 0, 0);
            acc[tl] = __builtin_amdgcn_mfma_f32_16x16x32_f16(al, bh, acc[tl], 0, 0, 0);
            acc[tl] = __builtin_amdgcn_mfma_f32_16x16x32_f16(ah, bl, acc[tl], 0, 0, 0);
        }
    }
    __syncthreads();  // barrier 1: cl ready

    // ---- mask words: ONE u32 per (lane, tile) covers all 4 regs ----
    unsigned cw[15];
    int cwsel = rh * 2 + (lk >> 1);
    #pragma unroll
    for (int tl = 0; tl < 15; ++tl)
        cw[tl] = cl[(ch * 240 + tl * 16 + lr) * 5 + cwsel];

    // ---- masked row max (wave-local over cols + one cross-half combine) ----
    float m[4];
    #pragma unroll
    for (int reg = 0; reg < 4; ++reg) {
        int shift = ((lk & 1) * 4 + reg) * 4;
        float mm = -INFINITY;
        #pragma unroll
        for (int tl = 0; tl < 15; ++tl)
            if ((cw[tl] >> shift) & 15u) mm = fmaxf(mm, acc[tl][reg]);
        #pragma unroll
        for (int msk = 1; msk <= 8; msk <<= 1)
            mm = fmaxf(mm, __shfl_xor(mm, msk, 64));
        if (lr == 0) mh[ch * 32 + rh * 16 + lk * 4 + reg] = mm;
    }
    __syncthreads();  // barrier 2
    #pragma unroll
    for (int reg = 0; reg < 4; ++reg) {
        int row = rh * 16 + lk * 4 + reg;
        m[reg] = fmaxf(mh[row], mh[32 + row]);
    }

    // ---- A = cnt * exp(G - m) -> LDS fp16; wave-local row sums ----
    float ps[4] = {0.f, 0.f, 0.f, 0.f};
    #pragma unroll
    for (int tl = 0; tl < 15; ++tl) {
        int col = ch * 240 + tl * 16 + lr;
        #pragma unroll
        for (int reg = 0; reg < 4; ++reg) {
            int shift = ((lk & 1) * 4 + reg) * 4;
            unsigned nib = (cw[tl] >> shift) & 15u;
            float a = 0.f;
            if (nib) a = (float)nib * __expf(acc[tl][reg] - m[reg]);
            ps[reg] += a;
            As[(rh * 16 + lk * 4 + reg) * 488 + col] = (_Float16)a;
        }
    }
    #pragma unroll
    for (int reg = 0; reg < 4; ++reg) {
        #pragma unroll
        for (int msk = 1; msk <= 8; msk <<= 1)
            ps[reg] += __shfl_xor(ps[reg], msk, 64);
        if (lr == 0) lsu[ch * 32 + rh * 16 + lk * 4 + reg] = ps[reg];
    }
    __syncthreads();  // barrier 3: As + lsu ready

    // ---- GEMM2: h = As(32x480) @ RW(480x128); B (RWT) direct from L2 ----
    int rh2 = w & 1, ch2 = w >> 1;
    f32x4 a2[4];
    #pragma unroll
    for (int i = 0; i < 4; ++i) a2[i] = (f32x4){0.f, 0.f, 0.f, 0.f};
    for (int kf2 = 0; kf2 < 15; ++kf2) {
        half8 af = *(const half8*)((const char*)As + (rh2 * 16 + lr) * 976 + kf2 * 64 + lk * 16);
        #pragma unroll
        for (int t2 = 0; t2 < 4; ++t2) {
            int col2 = ch2 * 64 + t2 * 16 + lr;
            const _Float16* bp = RWT + (size_t)col2 * 960 + kf2 * 32 + lk * 8;
            half8 bh = *(const half8*)bp;
            half8 bl = *(const half8*)(bp + 480);
            a2[t2] = __builtin_amdgcn_mfma_f32_16x16x32_f16(af, bh, a2[t2], 0, 0, 0);
            a2[t2] = __builtin_amdgcn_mfma_f32_16x16x32_f16(af, bl, a2[t2], 0, 0, 0);
        }
    }

    // ---- epilogue: scale by 1/l, write h ----
    #pragma unroll
    for (int reg = 0; reg < 4; ++reg) {
        int row = rh2 * 16 + lk * 4 + reg;
        float lv = lsu[row] + lsu[32 + row];
        float invl = (lv > 0.f) ? 1.f / lv : 0.f;
        #pragma unroll
        for (int t2 = 0; t2 < 4; ++t2)
            h[((size_t)nb * 32 + row) * HD + ch2 * 64 + t2 * 16 + lr] = a2[t2][reg] * invl;
    }
}

// K4: per-column sum / sumsq over rows (block-partial -> global atomics)
__global__ __launch_bounds__(256) void k_stats(
        const float* __restrict__ Hout, float* __restrict__ colsum,
        float* __restrict__ colsumsq) {
    __shared__ float ls[256], lq[256];
    int t = threadIdx.x;
    int c = t & 127, half = t >> 7;
    int rbase = blockIdx.x * 64;
    float sum = 0.f, sq = 0.f;
    #pragma unroll 4
    for (int i = 0; i < 32; ++i) {
        int r = rbase + half + i * 2;
        float v = Hout[(size_t)r * HD + c];
        sum += v;
        sq += v * v;
    }
    ls[t] = sum;
    lq[t] = sq;
    __syncthreads();
    if (t < 128) {
        sum = ls[t] + ls[t + 128];
        sq = lq[t] + lq[t + 128];
        atomicAdd(colsum + c, sum);
        atomicAdd(colsumsq + c, sq);
    }
}

// K5: out = tanh((h - mean) * rstd * gamma + beta), in place; fast tanh
__global__ __launch_bounds__(256) void k_apply(
        float* __restrict__ Hout, const float* __restrict__ colsum,
        const float* __restrict__ colsumsq, const float* __restrict__ gamma,
        const float* __restrict__ beta) {
    int idx = blockIdx.x * 256 + threadIdx.x;  // float4 index
    if (idx >= N_NODES * HD / 4) return;
    int c0 = (idx * 4) & 127;
    float4 hv4 = ((const float4*)Hout)[idx];
    const float inv = 1.f / (float)N_NODES;
    float hv[4] = {hv4.x, hv4.y, hv4.z, hv4.w};
    float o[4];
    #pragma unroll
    for (int j = 0; j < 4; ++j) {
        int c = c0 + j;
        float mean = colsum[c] * inv;
        float var = colsumsq[c] * inv - mean * mean;
        float rstd = rsqrtf(var + BN_EPS);
        float x = (hv[j] - mean) * rstd * gamma[c] + beta[c];
        o[j] = 1.f - 2.f / (__expf(2.f * x) + 1.f);
    }
    ((float4*)Hout)[idx] = make_float4(o[0], o[1], o[2], o[3]);
}

extern "C" void kernel_launch(void* const* d_in, const int* in_sizes, int n_in,
                              void* d_out, int out_size, void* d_ws, size_t ws_size,
                              hipStream_t stream) {
    const float* ent_emb  = (const float*)d_in[0];
    const float* rel_emb  = (const float*)d_in[1];
    const float* neigh_w  = (const float*)d_in[2];
    const float* bn_gamma = (const float*)d_in[3];
    const float* bn_beta  = (const float*)d_in[4];
    const int*   rel_id   = (const int*)d_in[5];
    const int*   dst      = (const int*)d_in[6];
    float* out = (float*)d_out;

    // workspace layout (4-byte words)
    unsigned* cntT   = (unsigned*)d_ws;                       // [1250*480*4] = 2,400,000
    float*    colsum = (float*)d_ws + 2400000;                // [128]
    float*    colsumsq = colsum + 128;                        // [128]
    _Float16* R_hl   = (_Float16*)((float*)d_ws + 2400256);   // [480*256] halfs
    _Float16* RWT    = (_Float16*)((float*)d_ws + 2461696);   // [128*960] halfs

    hipMemsetAsync(d_ws, 0, (size_t)2400256 * 4, stream);

    k_cnt<<<(N_EDGES + 255) / 256, 256, 0, stream>>>(dst, rel_id, cntT);
    k_rw<<<480, 128, 0, stream>>>(rel_emb, neigh_w, R_hl, RWT);
    k_fat<<<N_NODES / 32, 256, 0, stream>>>(ent_emb, R_hl, RWT, cntT, out);
    k_stats<<<N_NODES / 64, 256, 0, stream>>>(out, colsum, colsumsq);
    k_apply<<<N_NODES * HD / 4 / 256, 256, 0, stream>>>(out, colsum, colsumsq, bn_gamma, bn_beta);
}